// Round 1
// 1135.602 us; speedup vs baseline: 1.1501x; 1.1501x over previous
//
#include <hip/hip_runtime.h>
#include <hip/hip_bf16.h>
#include <stdint.h>

#define IN_DIM   4096
#define OUT_DIM  11008
#define M_DIM    8192      // B*S = 4*2048

typedef unsigned short u16;
typedef __bf16 bf16_t;
typedef bf16_t bf16x8 __attribute__((ext_vector_type(8)));
typedef float  f32x4  __attribute__((ext_vector_type(4)));
typedef u16    u16x8  __attribute__((ext_vector_type(8)));

static __device__ __forceinline__ u16 f2bf(float f) {
    __bf16 h = (__bf16)f;                    // fptrunc = round-to-nearest-even
    return __builtin_bit_cast(unsigned short, h);
}

// global -> LDS async copy, 16B per lane; lds must be the WAVE-UNIFORM base
// (HW writes to base + lane*16), gaddr is per-lane.
static __device__ __forceinline__ void async_copy16(void* lds_uniform, const void* gaddr) {
    __builtin_amdgcn_global_load_lds(
        (const __attribute__((address_space(1))) uint32_t*)(uintptr_t)gaddr,
        (__attribute__((address_space(3))) uint32_t*)(uintptr_t)lds_uniform,
        16, 0, 0);
}

// ---------------- fused prep kernel (unchanged) ----------------
#define XB_BLOCKS ((M_DIM * IN_DIM / 8) / 256)          // 16384
#define WB_BLOCKS ((OUT_DIM * IN_DIM / 8) / 256)        // 22016

__global__ void prep_kernel(const float* __restrict__ x, const float* __restrict__ w,
                            const float* __restrict__ scale,
                            u16x8* __restrict__ xb, u16x8* __restrict__ wb) {
    if (blockIdx.x < XB_BLOCKS) {
        int i = blockIdx.x * 256 + threadIdx.x;
        const float4* p = (const float4*)x + 2 * (size_t)i;
        float4 a = p[0];
        float4 b = p[1];
        u16x8 r;
        r[0] = f2bf(a.x); r[1] = f2bf(a.y); r[2] = f2bf(a.z); r[3] = f2bf(a.w);
        r[4] = f2bf(b.x); r[5] = f2bf(b.y); r[6] = f2bf(b.z); r[7] = f2bf(b.w);
        xb[i] = r;
    } else {
        int i = (blockIdx.x - XB_BLOCKS) * 256 + threadIdx.x;
        int g = i >> 4;                                    // (i*8)/128
        float s = fmaxf(fabsf(scale[g]), 1e-8f);
        u16 bs = f2bf(s);
        const float4* p = (const float4*)w + 2 * (size_t)i;
        float4 a = p[0];
        float4 b = p[1];
        u16x8 r;
        r[0] = bs | ((a.x < 0.f) ? 0x8000 : 0);
        r[1] = bs | ((a.y < 0.f) ? 0x8000 : 0);
        r[2] = bs | ((a.z < 0.f) ? 0x8000 : 0);
        r[3] = bs | ((a.w < 0.f) ? 0x8000 : 0);
        r[4] = bs | ((b.x < 0.f) ? 0x8000 : 0);
        r[5] = bs | ((b.y < 0.f) ? 0x8000 : 0);
        r[6] = bs | ((b.z < 0.f) ? 0x8000 : 0);
        r[7] = bs | ((b.w < 0.f) ? 0x8000 : 0);
        wb[i] = r;
    }
}

// ---------------- GEMM: 256x256 tile, BK=64, 8-phase counted-vmcnt schedule ----
// 512 threads = 8 waves (2M x 4N), per-wave 128x64 output = acc[8][4] (16x16x32).
// LDS 128 KiB: sA[2][256*64] + sB[2][256*64], chunk-XOR swizzle (T2, conflict-free,
// proven by SQ_LDS_BANK_CONFLICT=0 on the previous kernel).
// T3+T4: 8 phases / 2 K-tiles; per phase {ds_read subtile, stage 1 half-tile} ->
// barrier -> lgkmcnt(0) -> setprio(1) -> 16 MFMA -> setprio(0) -> barrier.
// vmcnt(4) ONLY at phases 4 and 8 (never 0 in the main loop).
//
// Staging schedule (iteration kt=2i; audited against read stripes):
//   reads:  ph1 LDA(b0,lo)+LDB(b0,lo)  ph2 LDB(b0,hi)  ph3 LDA(b0,hi)  ph4 -
//           ph5 LDA(b1,lo)+LDB(b1,lo)  ph6 LDB(b1,hi)  ph7 LDA(b1,hi)  ph8 -
//   stages: ph1 b1.A-hi(kt+1)  ph2 b1.B-hi(kt+1)  ph3 b0.B-lo(kt+2)  ph4 b0.A-lo(kt+2)
//           ph5 b0.A-hi(kt+2)  ph6 b0.B-hi(kt+2)  ph7 b1.B-lo(kt+3)  ph8 b1.A-lo(kt+3)
// Each stage target's last reader is >=1 barrier before the stage issue; each
// vmcnt(4) forces exactly the 8 loads the following 4 phases consume, leaving
// the newest 4 (just-issued half-tiles) in flight across the barrier.

#define BM 256
#define BN 256
#define NPID_M (M_DIM / BM)     // 32
#define NPID_N (OUT_DIM / BN)   // 43

#define BAR()        __builtin_amdgcn_s_barrier()
#define WAIT_VM(n)   asm volatile("s_waitcnt vmcnt(" #n ")" ::: "memory")
#define WAIT_LGKM(n) asm volatile("s_waitcnt lgkmcnt(" #n ")" ::: "memory")
#define PRIO(p)      __builtin_amdgcn_s_setprio(p)
#define SCHEDB()     __builtin_amdgcn_sched_barrier(0)

// stage instr j (0..3) covers rows [j*64 + wid*8, +8) of the 256-row region;
// LDS dest linear, global src pre-swizzled: gc = (lane&7) ^ (lane>>3)
#define STG_A(b, j, kt) async_copy16(&sA[b][((j)*64 + wid*8) * 64], \
                                     gA + (size_t)(j) * 64 * IN_DIM + ((kt) & 63) * 64)
#define STG_B(b, j, kt) async_copy16(&sB[b][((j)*64 + wid*8) * 64], \
                                     gB + (size_t)(j) * 64 * IN_DIM + ((kt) & 63) * 64)
#define STAGE_A(b, h, kt) do { STG_A(b, 2*(h), kt); STG_A(b, 2*(h)+1, kt); } while (0)
#define STAGE_B(b, h, kt) do { STG_B(b, 2*(h), kt); STG_B(b, 2*(h)+1, kt); } while (0)

// fragment reads: row&7 == row16&7 for every fragment row, so the swizzled
// chunk offset (sw0/sw1) is fragment-independent.
#define LDA(b, mh) do {                                                   \
    _Pragma("unroll")                                                     \
    for (int m_ = 0; m_ < 4; ++m_) {                                      \
      const int r_ = arb + ((mh)*4 + m_) * 16;                            \
      aF[m_][0] = *(const bf16x8*)&sA[b][r_ * 64 + sw0];                  \
      aF[m_][1] = *(const bf16x8*)&sA[b][r_ * 64 + sw1];                  \
    }                                                                     \
  } while (0)

#define LDB(b, nh, BF) do {                                               \
    _Pragma("unroll")                                                     \
    for (int n_ = 0; n_ < 2; ++n_) {                                      \
      const int r_ = brb + ((nh)*2 + n_) * 16;                            \
      BF[n_][0] = *(const bf16x8*)&sB[b][r_ * 64 + sw0];                  \
      BF[n_][1] = *(const bf16x8*)&sB[b][r_ * 64 + sw1];                  \
    }                                                                     \
  } while (0)

// one C-quadrant x K=64: 4 M-frags x 2 N-frags x 2 kslices = 16 MFMA.
// ks outer -> 8 independent MFMAs between dependent acc pairs.
#define MFMA_Q(mh, BF, nh) do {                                           \
    _Pragma("unroll")                                                     \
    for (int ks_ = 0; ks_ < 2; ++ks_)                                     \
      _Pragma("unroll")                                                   \
      for (int m_ = 0; m_ < 4; ++m_)                                      \
        _Pragma("unroll")                                                 \
        for (int n_ = 0; n_ < 2; ++n_)                                    \
          acc[(mh)*4 + m_][(nh)*2 + n_] =                                 \
              __builtin_amdgcn_mfma_f32_16x16x32_bf16(                    \
                  aF[m_][ks_], BF[n_][ks_],                               \
                  acc[(mh)*4 + m_][(nh)*2 + n_], 0, 0, 0);                \
  } while (0)

#define PH_TOP() do { BAR(); WAIT_LGKM(0); SCHEDB(); PRIO(1); } while (0)
#define PH_END() do { PRIO(0); BAR(); } while (0)

__global__ __launch_bounds__(512, 2) void gemm_kernel(const u16* __restrict__ A,
                                                      const u16* __restrict__ Bw,
                                                      const float* __restrict__ bias,
                                                      float* __restrict__ out) {
    __shared__ __align__(16) u16 sA[2][BM * 64];   // 64 KiB
    __shared__ __align__(16) u16 sB[2][BN * 64];   // 64 KiB

    // XCD-chunked bijective swizzle (nwg = 1376, 1376 % 8 == 0).
    // Row-major inside the chunk: each XCD keeps one A panel L2-hot,
    // B panels are shared across XCDs through L3 (172 = 4*43 -> same B cols).
    const int pid0  = blockIdx.x;
    const int pid   = (pid0 & 7) * (NPID_M * NPID_N / 8) + (pid0 >> 3);
    const int pid_m = pid / NPID_N;
    const int pid_n = pid - pid_m * NPID_N;
    const int m0 = pid_m * BM;
    const int n0 = pid_n * BN;

    const int tid  = threadIdx.x;
    const int wid  = tid >> 6;          // 0..7
    const int lane = tid & 63;
    const int wm   = (wid >> 2) * 128;  // wave M origin in tile
    const int wn   = (wid & 3) * 64;    // wave N origin

    // staging addresses (per-lane global, pre-swizzled chunk)
    const int lrow = lane >> 3;
    const int gc   = (lane & 7) ^ lrow;
    const u16* gA = A  + (size_t)(m0 + wid * 8 + lrow) * IN_DIM + gc * 8;
    const u16* gB = Bw + (size_t)(n0 + wid * 8 + lrow) * IN_DIM + gc * 8;

    // fragment read addressing
    const int row16 = lane & 15;
    const int quad  = lane >> 4;
    const int arb   = wm + row16;
    const int brb   = wn + row16;
    const int sw0   = ((0 * 4 + quad) ^ (row16 & 7)) * 8;   // ks=0 chunk (u16 offset)
    const int sw1   = ((1 * 4 + quad) ^ (row16 & 7)) * 8;   // ks=1 chunk

    f32x4 acc[8][4];
#pragma unroll
    for (int mt = 0; mt < 8; ++mt)
#pragma unroll
        for (int nt = 0; nt < 4; ++nt)
            acc[mt][nt] = (f32x4){0.f, 0.f, 0.f, 0.f};

    bf16x8 aF[4][2], bF0[2][2], bF1[2][2];

    // ---- prologue: buf0 fully, buf1 lo-halves; leave newest 4 loads in flight
    STAGE_A(0, 0, 0); STAGE_A(0, 1, 0);
    STAGE_B(0, 0, 0); STAGE_B(0, 1, 0);
    STAGE_B(1, 0, 1); STAGE_A(1, 0, 1);
    WAIT_VM(4);
    BAR();

    for (int i = 0; i < IN_DIM / 128; ++i) {      // 32 iterations, 2 K-tiles each
        const int kt = 2 * i;
        // ---- phase 1: buf0 quadrant (Mlo, Nlo)
        LDA(0, 0); LDB(0, 0, bF0);                // 12 ds_read_b128
        STAGE_A(1, 1, kt + 1);
        WAIT_LGKM(8);
        PH_TOP(); MFMA_Q(0, bF0, 0); PH_END();
        // ---- phase 2: buf0 (Mlo, Nhi)
        LDB(0, 1, bF1);
        STAGE_B(1, 1, kt + 1);
        PH_TOP(); MFMA_Q(0, bF1, 1); PH_END();
        // ---- phase 3: buf0 (Mhi, Nlo)
        LDA(0, 1);
        STAGE_B(0, 0, kt + 2);
        PH_TOP(); MFMA_Q(1, bF0, 0); PH_END();
        // ---- phase 4: buf0 (Mhi, Nhi) — counted vmcnt, NOT 0
        STAGE_A(0, 0, kt + 2);
        BAR(); WAIT_LGKM(0); SCHEDB(); PRIO(1);
        MFMA_Q(1, bF1, 1);
        PRIO(0); WAIT_VM(4); BAR();
        // ---- phase 5: buf1 (Mlo, Nlo)
        LDA(1, 0); LDB(1, 0, bF0);
        STAGE_A(0, 1, kt + 2);
        WAIT_LGKM(8);
        PH_TOP(); MFMA_Q(0, bF0, 0); PH_END();
        // ---- phase 6: buf1 (Mlo, Nhi)
        LDB(1, 1, bF1);
        STAGE_B(0, 1, kt + 2);
        PH_TOP(); MFMA_Q(0, bF1, 1); PH_END();
        // ---- phase 7: buf1 (Mhi, Nlo)
        LDA(1, 1);
        STAGE_B(1, 0, kt + 3);
        PH_TOP(); MFMA_Q(1, bF0, 0); PH_END();
        // ---- phase 8: buf1 (Mhi, Nhi) — counted vmcnt
        STAGE_A(1, 0, kt + 3);
        BAR(); WAIT_LGKM(0); SCHEDB(); PRIO(1);
        MFMA_Q(1, bF1, 1);
        PRIO(0); WAIT_VM(4); BAR();
        // last iteration stages kt 64/65 -> (kt&63) wraps to 0/1: dead data,
        // never consumed; avoids a peeled epilogue iteration.
    }
    WAIT_VM(0);   // drain LDS-DMA before wave can exit

    // epilogue: C/D layout col = lane&15, row = quad*4 + reg (same as verified)
#pragma unroll
    for (int nt = 0; nt < 4; ++nt) {
        int col  = n0 + wn + nt * 16 + row16;
        float bv = bias[col];
#pragma unroll
        for (int mt = 0; mt < 8; ++mt) {
            int row = m0 + wm + mt * 16 + quad * 4;
            float* po = out + (size_t)row * OUT_DIM + col;
#pragma unroll
            for (int r = 0; r < 4; ++r)
                __builtin_nontemporal_store(acc[mt][nt][r] + bv, po + (size_t)r * OUT_DIM);
        }
    }
}

// ---------------- emergency fallback (ws too small): slow but correct ----------------
__global__ void naive_kernel(const float* __restrict__ x, const float* __restrict__ wt,
                             const float* __restrict__ bias, const float* __restrict__ scale,
                             float* __restrict__ out) {
    long idx = (long)blockIdx.x * 256 + threadIdx.x;
    if (idx >= (long)M_DIM * OUT_DIM) return;
    int m = (int)(idx / OUT_DIM);
    int o = (int)(idx % OUT_DIM);
    const float* xr = x + (size_t)m * IN_DIM;
    const float* wr = wt + (size_t)o * IN_DIM;
    float acc = 0.f;
    for (int gb = 0; gb < IN_DIM / 128; ++gb) {
        float s = fmaxf(fabsf(scale[o * (IN_DIM / 128) + gb]), 1e-8f);
        float part = 0.f;
        for (int k = 0; k < 128; ++k) {
            float wv = wr[gb * 128 + k];
            part += (wv >= 0.f) ? xr[gb * 128 + k] : -xr[gb * 128 + k];
        }
        acc += part * s;
    }
    out[idx] = acc + bias[o];
}

extern "C" void kernel_launch(void* const* d_in, const int* in_sizes, int n_in,
                              void* d_out, int out_size, void* d_ws, size_t ws_size,
                              hipStream_t stream) {
    const float* x     = (const float*)d_in[0];
    const float* wt    = (const float*)d_in[1];
    const float* bias  = (const float*)d_in[2];
    const float* scale = (const float*)d_in[3];
    float* out = (float*)d_out;

    const size_t xb_bytes = (size_t)M_DIM * IN_DIM * sizeof(u16);     // 67 MB
    const size_t wb_bytes = (size_t)OUT_DIM * IN_DIM * sizeof(u16);   // 90 MB

    if (ws_size >= xb_bytes + wb_bytes) {
        u16* xb = (u16*)d_ws;
        u16* wb = (u16*)((char*)d_ws + xb_bytes);

        prep_kernel<<<XB_BLOCKS + WB_BLOCKS, 256, 0, stream>>>(
            x, wt, scale, (u16x8*)xb, (u16x8*)wb);

        gemm_kernel<<<NPID_M * NPID_N, 512, 0, stream>>>(xb, wb, bias, out);
    } else {
        long total = (long)M_DIM * OUT_DIM;
        int blocks = (int)((total + 255) / 256);
        naive_kernel<<<blocks, 256, 0, stream>>>(x, wt, bias, scale, out);
    }
}

// Round 3
// 1083.656 us; speedup vs baseline: 1.2053x; 1.0479x over previous
//
#include <hip/hip_runtime.h>
#include <hip/hip_bf16.h>
#include <stdint.h>

#define IN_DIM   4096
#define OUT_DIM  11008
#define M_DIM    8192      // B*S = 4*2048

typedef unsigned short u16;
typedef __bf16 bf16_t;
typedef bf16_t bf16x8 __attribute__((ext_vector_type(8)));
typedef float  f32x4  __attribute__((ext_vector_type(4)));
typedef u16    u16x8  __attribute__((ext_vector_type(8)));

static __device__ __forceinline__ u16 f2bf(float f) {
    __bf16 h = (__bf16)f;                    // fptrunc = round-to-nearest-even
    return __builtin_bit_cast(unsigned short, h);
}

// global -> LDS async copy, 16B per lane; lds must be the WAVE-UNIFORM base
// (HW writes to base + lane*16), gaddr is per-lane.
static __device__ __forceinline__ void async_copy16(void* lds_uniform, const void* gaddr) {
    __builtin_amdgcn_global_load_lds(
        (const __attribute__((address_space(1))) uint32_t*)(uintptr_t)gaddr,
        (__attribute__((address_space(3))) uint32_t*)(uintptr_t)lds_uniform,
        16, 0, 0);
}

// ---------------- fused prep kernel: grid-stride + NT loads ----------------
// NOTE: __builtin_nontemporal_load requires a clang vector type, NOT HIP's
// float4 struct — use the f32x4 ext_vector_type.
#define PREP_BLOCKS 4096

__global__ __launch_bounds__(256) void prep_kernel(const float* __restrict__ x,
                                                   const float* __restrict__ w,
                                                   const float* __restrict__ scale,
                                                   u16x8* __restrict__ xb,
                                                   u16x8* __restrict__ wb) {
    const int XB_UNITS  = M_DIM * IN_DIM / 8;                 // 4194304
    const int TOT_UNITS = XB_UNITS + OUT_DIM * IN_DIM / 8;    // 9830400
    for (int u = blockIdx.x * 256 + threadIdx.x; u < TOT_UNITS; u += PREP_BLOCKS * 256) {
        if (u < XB_UNITS) {
            const f32x4* p = (const f32x4*)x + 2 * (size_t)u;
            f32x4 a = __builtin_nontemporal_load(p);
            f32x4 b = __builtin_nontemporal_load(p + 1);
            u16x8 r;
            r[0] = f2bf(a[0]); r[1] = f2bf(a[1]); r[2] = f2bf(a[2]); r[3] = f2bf(a[3]);
            r[4] = f2bf(b[0]); r[5] = f2bf(b[1]); r[6] = f2bf(b[2]); r[7] = f2bf(b[3]);
            xb[u] = r;
        } else {
            int i = u - XB_UNITS;
            int g = i >> 4;                                    // (i*8)/128
            float s = fmaxf(fabsf(scale[g]), 1e-8f);
            u16 bs = f2bf(s);
            const f32x4* p = (const f32x4*)w + 2 * (size_t)i;
            f32x4 a = __builtin_nontemporal_load(p);
            f32x4 b = __builtin_nontemporal_load(p + 1);
            u16x8 r;
            r[0] = bs | ((a[0] < 0.f) ? 0x8000 : 0);
            r[1] = bs | ((a[1] < 0.f) ? 0x8000 : 0);
            r[2] = bs | ((a[2] < 0.f) ? 0x8000 : 0);
            r[3] = bs | ((a[3] < 0.f) ? 0x8000 : 0);
            r[4] = bs | ((b[0] < 0.f) ? 0x8000 : 0);
            r[5] = bs | ((b[1] < 0.f) ? 0x8000 : 0);
            r[6] = bs | ((b[2] < 0.f) ? 0x8000 : 0);
            r[7] = bs | ((b[3] < 0.f) ? 0x8000 : 0);
            wb[i] = r;
        }
    }
}

// ---------------- GEMM: 256x256 tile, BK=64, ONE-barrier 8-body schedule ----
// 512 threads = 8 waves (2M x 4N), per-wave 128x64 = acc[8][4] (16x16x32 bf16).
// vs 2-barrier version: ONE s_barrier per body (8/iter, was 16). Each body:
//   lgkmcnt(0) -> setprio(1) -> 16 MFMA -> setprio(0) -> ds_reads for NEXT body
//   -> stage 1 region (2 DMA) -> [vmcnt(10)] -> s_barrier
// Wave slip overlaps ds_read issue + LDS pipe with other waves' MFMA (the
// 2-barrier form serializes them, capping MfmaUtil at ~45% = measured 47%).
//
// Region granularity (exact read sets):
//   A02 = rows {0-63,128-191}   read ONLY by LDA(b,0)   (wave rows wm..wm+63)
//   A13 = rows {64-127,192-255} read ONLY by LDA(b,1)
//   B02 = rows {0-31,64-95,128-159,192-223}  read ONLY by LDB(b,0)
//   B13 = rows {32-63,96-127,160-191,224-255} read ONLY by LDB(b,1)
// B slabs are REMAPPED so each 2-DMA stage unit covers exactly B02 or B13.
//
// Stage schedule (iter kt=2i), one unit per body; VM(10) at bodies 0,2,3,4,6,7:
//   b0: A02(0,kt+2)+VM  b1: B02(0,kt+2)      b2: B13(0,kt+2)+VM  b3: A13(0,kt+2)+VM
//   b4: A02(1,kt+3)+VM  b5: B02(1,kt+3)      b6: B13(1,kt+3)+VM  b7: A13(1,kt+3)+VM
// Audited: every region forced (oldest-first vmcnt drain) exactly >=1 barrier
// before its first read-issue; issue-to-force distance 5-6 bodies; 5 units
// (10 loads) always in flight. Every stage target >=1 barrier + lgkm-drain
// after the last reader of its old contents.

#define BM 256
#define BN 256
#define NPID_M (M_DIM / BM)     // 32
#define NPID_N (OUT_DIM / BN)   // 43

#define BAR()        __builtin_amdgcn_s_barrier()
#define WAIT_VM(n)   asm volatile("s_waitcnt vmcnt(" #n ")" ::: "memory")
#define WAIT_LGKM(n) asm volatile("s_waitcnt lgkmcnt(" #n ")" ::: "memory")
#define PRIO(p)      __builtin_amdgcn_s_setprio(p)
#define SCHEDB()     __builtin_amdgcn_sched_barrier(0)

// A slab j (0..3): rows j*64 + wid*8 + lrow  (natural)
#define STG_A(b, j, kt) async_copy16(&sA[b][((j)*64 + wid*8) * 64], \
                                     gA + (size_t)(j) * 64 * IN_DIM + ((kt) & 63) * 64)
// B slab j: rows (j>>1)*128 + (j&1)*32 + (wid>>2)*64 + (wid&3)*8 + lrow
// -> slab0 = {0-31,64-95}, slab1 = {32-63,96-127}, slab2/3 = +128. Rows land at
// their NATURAL LDS offset (row*64), only the DMA->row ORDER is remapped.
#define ROWB0(j) (((j) >> 1) * 128 + ((j) & 1) * 32)
#define STG_B(b, j, kt) async_copy16(&sB[b][(ROWB0(j) + (wid>>2)*64 + (wid&3)*8) * 64], \
                                     gB + (size_t)ROWB0(j) * IN_DIM + ((kt) & 63) * 64)

#define STAGE_A02(b, kt) do { STG_A(b, 0, kt); STG_A(b, 2, kt); } while (0)
#define STAGE_A13(b, kt) do { STG_A(b, 1, kt); STG_A(b, 3, kt); } while (0)
#define STAGE_B02(b, kt) do { STG_B(b, 0, kt); STG_B(b, 2, kt); } while (0)
#define STAGE_B13(b, kt) do { STG_B(b, 1, kt); STG_B(b, 3, kt); } while (0)

// fragment reads: row&7 == row16&7 for every fragment row, so the swizzled
// chunk offset (sw0/sw1) is fragment-independent.
#define LDA(b, mh) do {                                                   \
    _Pragma("unroll")                                                     \
    for (int m_ = 0; m_ < 4; ++m_) {                                      \
      const int r_ = arb + ((mh)*4 + m_) * 16;                            \
      aF[m_][0] = *(const bf16x8*)&sA[b][r_ * 64 + sw0];                  \
      aF[m_][1] = *(const bf16x8*)&sA[b][r_ * 64 + sw1];                  \
    }                                                                     \
  } while (0)

#define LDB(b, nh, BF) do {                                               \
    _Pragma("unroll")                                                     \
    for (int n_ = 0; n_ < 2; ++n_) {                                      \
      const int r_ = brb + ((nh)*2 + n_) * 16;                            \
      BF[n_][0] = *(const bf16x8*)&sB[b][r_ * 64 + sw0];                  \
      BF[n_][1] = *(const bf16x8*)&sB[b][r_ * 64 + sw1];                  \
    }                                                                     \
  } while (0)

// one C-quadrant x K=64: 4 M-frags x 2 N-frags x 2 kslices = 16 MFMA.
#define MFMA_Q(mh, BF, nh) do {                                           \
    _Pragma("unroll")                                                     \
    for (int ks_ = 0; ks_ < 2; ++ks_)                                     \
      _Pragma("unroll")                                                   \
      for (int m_ = 0; m_ < 4; ++m_)                                      \
        _Pragma("unroll")                                                 \
        for (int n_ = 0; n_ < 2; ++n_)                                    \
          acc[(mh)*4 + m_][(nh)*2 + n_] =                                 \
              __builtin_amdgcn_mfma_f32_16x16x32_bf16(                    \
                  aF[m_][ks_], BF[n_][ks_],                               \
                  acc[(mh)*4 + m_][(nh)*2 + n_], 0, 0, 0);                \
  } while (0)

// body top: wait own ds_reads from previous body, pin, MFMA at high prio
#define MFMA_TOP(mh, BF, nh) do {                                         \
    WAIT_LGKM(0); SCHEDB();                                               \
    PRIO(1); MFMA_Q(mh, BF, nh); PRIO(0); SCHEDB();                       \
  } while (0)

__global__ __launch_bounds__(512, 2) void gemm_kernel(const u16* __restrict__ A,
                                                      const u16* __restrict__ Bw,
                                                      const float* __restrict__ bias,
                                                      float* __restrict__ out) {
    __shared__ __align__(16) u16 sA[2][BM * 64];   // 64 KiB
    __shared__ __align__(16) u16 sB[2][BN * 64];   // 64 KiB

    // XCD-chunked bijective swizzle (nwg = 1376, 1376 % 8 == 0).
    const int pid0  = blockIdx.x;
    const int pid   = (pid0 & 7) * (NPID_M * NPID_N / 8) + (pid0 >> 3);
    const int pid_m = pid / NPID_N;
    const int pid_n = pid - pid_m * NPID_N;
    const int m0 = pid_m * BM;
    const int n0 = pid_n * BN;

    const int tid  = threadIdx.x;
    const int wid  = tid >> 6;          // 0..7
    const int lane = tid & 63;
    const int wm   = (wid >> 2) * 128;  // wave M origin in tile
    const int wn   = (wid & 3) * 64;    // wave N origin

    // staging addresses (per-lane global, pre-swizzled chunk). Base row mod 8
    // is 0 for both A and B slabs, so gc = (lane&7) ^ lrow for both.
    const int lrow = lane >> 3;
    const int gc   = (lane & 7) ^ lrow;
    const u16* gA = A  + (size_t)(m0 + wid * 8 + lrow) * IN_DIM + gc * 8;
    const u16* gB = Bw + (size_t)(n0 + (wid >> 2) * 64 + (wid & 3) * 8 + lrow) * IN_DIM + gc * 8;

    // fragment read addressing
    const int row16 = lane & 15;
    const int quad  = lane >> 4;
    const int arb   = wm + row16;
    const int brb   = wn + row16;
    const int sw0   = ((0 * 4 + quad) ^ (row16 & 7)) * 8;   // ks=0 chunk (u16 offset)
    const int sw1   = ((1 * 4 + quad) ^ (row16 & 7)) * 8;   // ks=1 chunk

    f32x4 acc[8][4];
#pragma unroll
    for (int mt = 0; mt < 8; ++mt)
#pragma unroll
        for (int nt = 0; nt < 4; ++nt)
            acc[mt][nt] = (f32x4){0.f, 0.f, 0.f, 0.f};

    bf16x8 aF[4][2], bF0[2][2], bF1[2][2];

    // ---- prologue: 8 stage units (16 loads); force first 3 (A02/B02/B13 of
    // buf0) -> 10 left in flight = exact steady-state queue; then pre-reads.
    STAGE_A02(0, 0); STAGE_B02(0, 0); STAGE_B13(0, 0); STAGE_A13(0, 0);
    STAGE_A02(1, 1); STAGE_B02(1, 1); STAGE_B13(1, 1); STAGE_A13(1, 1);
    WAIT_VM(10);
    BAR();
    LDA(0, 0); LDB(0, 0, bF0);          // frags for body0's MFMA

    for (int i = 0; i < IN_DIM / 128; ++i) {      // 32 iterations, 2 K-tiles each
        const int kt = 2 * i;
        // body0: MFMA1 = buf0 (Mlo,Nlo)
        MFMA_TOP(0, bF0, 0);
        LDB(0, 1, bF1);
        STAGE_A02(0, kt + 2); WAIT_VM(10); BAR();
        // body1: MFMA2 = buf0 (Mlo,Nhi)
        MFMA_TOP(0, bF1, 1);
        LDA(0, 1);
        STAGE_B02(0, kt + 2); BAR();
        // body2: MFMA3 = buf0 (Mhi,Nlo)
        MFMA_TOP(1, bF0, 0);
        STAGE_B13(0, kt + 2); WAIT_VM(10); BAR();
        // body3: MFMA4 = buf0 (Mhi,Nhi)
        MFMA_TOP(1, bF1, 1);
        LDA(1, 0); LDB(1, 0, bF0);
        STAGE_A13(0, kt + 2); WAIT_VM(10); BAR();
        // body4: MFMA5 = buf1 (Mlo,Nlo)
        MFMA_TOP(0, bF0, 0);
        LDB(1, 1, bF1);
        STAGE_A02(1, kt + 3); WAIT_VM(10); BAR();
        // body5: MFMA6 = buf1 (Mlo,Nhi)
        MFMA_TOP(0, bF1, 1);
        LDA(1, 1);
        STAGE_B02(1, kt + 3); BAR();
        // body6: MFMA7 = buf1 (Mhi,Nlo)
        MFMA_TOP(1, bF0, 0);
        STAGE_B13(1, kt + 3); WAIT_VM(10); BAR();
        // body7: MFMA8 = buf1 (Mhi,Nhi); pre-reads for next iter's body0
        MFMA_TOP(1, bF1, 1);
        LDA(0, 0); LDB(0, 0, bF0);
        STAGE_A13(1, kt + 3); WAIT_VM(10); BAR();
        // last iteration stages (kt&63)-wrapped dead data; its pre-reads load
        // dead frags never consumed by MFMA. Uniform loop, no peeled tail.
    }
    WAIT_VM(0);     // drain LDS-DMA before epilogue/exit
    WAIT_LGKM(0);   // drain final pre-reads

    // epilogue: C/D layout col = lane&15, row = quad*4 + reg (verified layout)
#pragma unroll
    for (int nt = 0; nt < 4; ++nt) {
        int col  = n0 + wn + nt * 16 + row16;
        float bv = bias[col];
#pragma unroll
        for (int mt = 0; mt < 8; ++mt) {
            int row = m0 + wm + mt * 16 + quad * 4;
            float* po = out + (size_t)row * OUT_DIM + col;
#pragma unroll
            for (int r = 0; r < 4; ++r)
                __builtin_nontemporal_store(acc[mt][nt][r] + bv, po + (size_t)r * OUT_DIM);
        }
    }
}

// ---------------- emergency fallback (ws too small): slow but correct ----------------
__global__ void naive_kernel(const float* __restrict__ x, const float* __restrict__ wt,
                             const float* __restrict__ bias, const float* __restrict__ scale,
                             float* __restrict__ out) {
    long idx = (long)blockIdx.x * 256 + threadIdx.x;
    if (idx >= (long)M_DIM * OUT_DIM) return;
    int m = (int)(idx / OUT_DIM);
    int o = (int)(idx % OUT_DIM);
    const float* xr = x + (size_t)m * IN_DIM;
    const float* wr = wt + (size_t)o * IN_DIM;
    float acc = 0.f;
    for (int gb = 0; gb < IN_DIM / 128; ++gb) {
        float s = fmaxf(fabsf(scale[o * (IN_DIM / 128) + gb]), 1e-8f);
        float part = 0.f;
        for (int k = 0; k < 128; ++k) {
            float wv = wr[gb * 128 + k];
            part += (wv >= 0.f) ? xr[gb * 128 + k] : -xr[gb * 128 + k];
        }
        acc += part * s;
    }
    out[idx] = acc + bias[o];
}

extern "C" void kernel_launch(void* const* d_in, const int* in_sizes, int n_in,
                              void* d_out, int out_size, void* d_ws, size_t ws_size,
                              hipStream_t stream) {
    const float* x     = (const float*)d_in[0];
    const float* wt    = (const float*)d_in[1];
    const float* bias  = (const float*)d_in[2];
    const float* scale = (const float*)d_in[3];
    float* out = (float*)d_out;

    const size_t xb_bytes = (size_t)M_DIM * IN_DIM * sizeof(u16);     // 67 MB
    const size_t wb_bytes = (size_t)OUT_DIM * IN_DIM * sizeof(u16);   // 90 MB

    if (ws_size >= xb_bytes + wb_bytes) {
        u16* xb = (u16*)d_ws;
        u16* wb = (u16*)((char*)d_ws + xb_bytes);

        prep_kernel<<<PREP_BLOCKS, 256, 0, stream>>>(
            x, wt, scale, (u16x8*)xb, (u16x8*)wb);

        gemm_kernel<<<NPID_M * NPID_N, 512, 0, stream>>>(xb, wb, bias, out);
    } else {
        long total = (long)M_DIM * OUT_DIM;
        int blocks = (int)((total + 255) / 256);
        naive_kernel<<<blocks, 256, 0, stream>>>(x, wt, bias, scale, out);
    }
}